// Round 2
// baseline (400.976 us; speedup 1.0000x reference)
//
#include <hip/hip_runtime.h>
#include <hip/hip_bf16.h>

typedef __bf16 bf16x8 __attribute__((ext_vector_type(8)));
typedef __bf16 bf16x4 __attribute__((ext_vector_type(4)));
typedef float  floatx4 __attribute__((ext_vector_type(4)));

#define SH  2097152ll  // per-batch plane: 2048*1024
#define MSH 8388608ll  // full Q/K plane: 8192*1024
#define SS  4194304ll  // per-batch score plane: 2048*2048

// Async global->LDS, 16 B per lane. LDS dest is wave-uniform base + lane*16.
#define GLOAD16(gp, lp)                                                        \
  __builtin_amdgcn_global_load_lds(                                            \
      (const __attribute__((address_space(1))) void*)(gp),                     \
      (__attribute__((address_space(3))) void*)(lp), 16, 0, 0)

// ---------------------------------------------------------------------------
// 256xBN GEMM core, 512 threads = 8 waves (2M x 4N). Wave w owns a
// 128 x (BN/4) sub-tile as 8 x (BN/64) 16x16x32 bf16 MFMA fragments.
// A: M x K row-major bf16, B: N x K row-major bf16, BK=64.
// Double-buffered LDS + COUNTED vmcnt (T4): tile t+1's global_load_lds stay
// in flight across tile t's MFMA phases; vmcnt never drains to 0 mid-loop.
// LDS XOR swizzle (proven in prior rounds, SQ_LDS_BANK_CONFLICT == 0):
// logical 16B chunk c of row r stored at c ^ (r&7); staging lane pre-swizzles
// the GLOBAL source chunk (lane&7)^(lane>>3) so LDS dest stays linear.
// ---------------------------------------------------------------------------
template <int BN>
__device__ __forceinline__ void gemm_core8(
    const __bf16* __restrict__ A, const __bf16* __restrict__ B,
    __bf16* As, __bf16* Bs, floatx4 (&acc)[8][BN / 64],
    int m0, int n0, int Kd, int lda, int ldb, int tid) {
  constexpr int NREP = BN / 64;   // N fragments per wave
  constexpr int NB   = BN / 64;   // B-tile loads per thread per K-step
  const int lane = tid & 63, w = tid >> 6;
  const int wm = w >> 2, wn = w & 3;
  const int lo = lane & 15, quad = lane >> 4;
  const int lrow = lane >> 3;                 // 0..7
  const int lcol = ((lane & 7) ^ lrow) * 8;   // XOR-swizzled global chunk
  const int x7 = lo & 7;
  const __bf16* ap = A + (size_t)(m0 + w * 8 + lrow) * lda + lcol;
  const __bf16* bp = B + (size_t)(n0 + w * 8 + lrow) * ldb + lcol;
  __bf16* asw = As + (w * 8) * 64;
  __bf16* bsw = Bs + (w * 8) * 64;

#define STAGE8(d, kk)                                                          \
  {                                                                            \
    _Pragma("unroll") for (int l = 0; l < 4; l++)                              \
        GLOAD16(ap + (size_t)(l * 64) * lda + (kk),                            \
                asw + (d) * (256 * 64) + l * (64 * 64));                       \
    _Pragma("unroll") for (int l = 0; l < NB; l++)                             \
        GLOAD16(bp + (size_t)(l * 64) * ldb + (kk),                            \
                bsw + (d) * (BN * 64) + l * (64 * 64));                        \
  }

  const int NT = Kd >> 6;
  STAGE8(0, 0)
  for (int t = 0; t < NT; t++) {
    const int cur = t & 1;
    if (t + 1 < NT) {
      STAGE8(cur ^ 1, (t + 1) * 64)
      // Counted wait: tile t's (4+NB) loads done, tile t+1's stay in flight.
      if constexpr (BN == 256)
        asm volatile("s_waitcnt vmcnt(8)" ::: "memory");
      else
        asm volatile("s_waitcnt vmcnt(6)" ::: "memory");
    } else {
      asm volatile("s_waitcnt vmcnt(0)" ::: "memory");
    }
    __builtin_amdgcn_s_barrier();
    __builtin_amdgcn_sched_barrier(0);
    const __bf16* Ab = As + cur * (256 * 64);
    const __bf16* Bb = Bs + cur * (BN * 64);
#pragma unroll
    for (int kq = 0; kq < 2; kq++) {
      bf16x8 af[8];
#pragma unroll
      for (int mt = 0; mt < 8; mt++)
        af[mt] = *(const bf16x8*)
            &Ab[(wm * 128 + mt * 16 + lo) * 64 + (((kq * 4 + quad) ^ x7) * 8)];
#pragma unroll
      for (int nh = 0; nh < NREP / 2; nh++) {
        bf16x8 bf2[2];
#pragma unroll
        for (int j = 0; j < 2; j++)
          bf2[j] = *(const bf16x8*)
              &Bb[(wn * (BN / 4) + (nh * 2 + j) * 16 + lo) * 64 +
                  (((kq * 4 + quad) ^ x7) * 8)];
        __builtin_amdgcn_s_setprio(1);
#pragma unroll
        for (int mt = 0; mt < 8; mt++)
#pragma unroll
          for (int j = 0; j < 2; j++)
            acc[mt][nh * 2 + j] = __builtin_amdgcn_mfma_f32_16x16x32_bf16(
                af[mt], bf2[j], acc[mt][nh * 2 + j], 0, 0, 0);
        __builtin_amdgcn_s_setprio(0);
      }
    }
    __builtin_amdgcn_s_barrier();
    __builtin_amdgcn_sched_barrier(0);
  }
#undef STAGE8
}

#define ACC_INIT(NR)                                                           \
  floatx4 acc[8][NR];                                                          \
  _Pragma("unroll") for (int mt = 0; mt < 8; mt++)                             \
      _Pragma("unroll") for (int nt = 0; nt < NR; nt++)                        \
          acc[mt][nt] = (floatx4){0.f, 0.f, 0.f, 0.f};

#define EPI_IDS()                                                              \
  const int lane = tid & 63, w = tid >> 6, wm = w >> 2, wn = w & 3;            \
  const int lo = lane & 15, quad = lane >> 4;

// QKV' projection: C[8192 x 3072] = Xb @ B^T. Chunks: 0=Q(+bq), 1=K(+bk),
// 2=VWo(+bv@Wo) stored TRANSPOSED per batch (VWoT[e][s]). V itself is never
// materialized: VWo = X @ (Wv@Wo) + bv@Wo.  grid (24, 32), 512 thr.
__global__ __launch_bounds__(512, 2) void qkv_k(
    const __bf16* __restrict__ Xb, const __bf16* __restrict__ Wt,
    const __bf16* __restrict__ MTb, const float* __restrict__ bq,
    const float* __restrict__ bk, const float* __restrict__ bvwo,
    __bf16* __restrict__ QK, __bf16* __restrict__ VWoT) {
  __shared__ __bf16 As[2 * 256 * 64];
  __shared__ __bf16 Bs[2 * 128 * 64];
  const int tid = threadIdx.x;
  ACC_INIT(2);
  const int m0 = blockIdx.y * 256;
  const int n0 = blockIdx.x * 128;
  const int chunk = n0 >> 10;                       // 0=Q 1=K 2=VWo
  const __bf16* Bbase = chunk < 2 ? Wt : MTb;
  const int n0l = chunk < 2 ? n0 : n0 - 2048;
  gemm_core8<128>(Xb, Bbase, As, Bs, acc, m0, n0l, 1024, 1024, 1024, tid);
  EPI_IDS();
  if (chunk < 2) {
    const float* bp = chunk == 0 ? bq : bk;
#pragma unroll
    for (int mt = 0; mt < 8; mt++) {
      const int gmb = m0 + wm * 128 + mt * 16 + quad * 4;
#pragma unroll
      for (int nt = 0; nt < 2; nt++) {
        const int gnl = (n0 + wn * 32 + nt * 16 + lo) & 1023;
        const float b_ = bp[gnl];
#pragma unroll
        for (int r = 0; r < 4; r++)
          QK[(size_t)chunk * MSH + (size_t)(gmb + r) * 1024 + gnl] =
              (__bf16)(acc[mt][nt][r] + b_);
      }
    }
  } else {
    const int bz = m0 >> 11;
    const int sb = (m0 & 2047) + wm * 128;
#pragma unroll
    for (int mt = 0; mt < 8; mt++) {
      const int sl = sb + mt * 16 + quad * 4;
#pragma unroll
      for (int nt = 0; nt < 2; nt++) {
        const int e = (n0 + wn * 32 + nt * 16 + lo) & 1023;
        const float b_ = bvwo[e];
        bf16x4 pk;
#pragma unroll
        for (int r = 0; r < 4; r++) pk[r] = (__bf16)(acc[mt][nt][r] + b_);
        *(bf16x4*)(VWoT + (size_t)bz * SH + (size_t)e * 2048 + sl) = pk;
      }
    }
  }
}

// MID (exp only now): E = exp(maskbit ? 1e-20 : QK^T/32) bf16 + rowsum
// atomics into L. grid (64,1,4): xcd = x&7 owns a 2x4 tile patch
// (A 2x512KB + B 4x512KB = 3MB <= 4MiB private L2).
__global__ __launch_bounds__(512, 2) void mid_k(
    const __bf16* __restrict__ QK, __bf16* __restrict__ E,
    const unsigned* __restrict__ Pk, float* __restrict__ L) {
  __shared__ __bf16 As[2 * 256 * 64];
  __shared__ __bf16 Bs[2 * 256 * 64];
  const int tid = threadIdx.x;
  ACC_INIT(4);
  const int bz = blockIdx.z;
  const int sid = blockIdx.x;
  const int xcd = sid & 7, k = sid >> 3;            // k 0..7
  const int m0 = ((xcd >> 1) * 2 + (k >> 2)) * 256; // q-tile 0..7
  const int n0 = ((xcd & 1) * 4 + (k & 3)) * 256;   // k-tile 0..7
  gemm_core8<256>(QK + bz * SH, QK + MSH + bz * SH, As, Bs, acc,
                  m0, n0, 1024, 1024, 1024, tid);
  EPI_IDS();
  const unsigned* Pb = Pk + (size_t)bz * 131072;
#pragma unroll
  for (int mt = 0; mt < 8; mt++) {
    const int gmb = m0 + wm * 128 + mt * 16 + quad * 4;
#pragma unroll
    for (int r = 0; r < 4; r++) {
      const int gm = gmb + r;
      float rowpart = 0.f;
#pragma unroll
      for (int nt = 0; nt < 4; nt++) {
        const int gn = n0 + wn * 64 + nt * 16 + lo;
        const unsigned wd = Pb[(size_t)gm * 64 + (gn >> 5)];
        float s = acc[mt][nt][r] * 0.03125f;
        if ((wd >> (gn & 31)) & 1u) s = 1e-20f;
        const float e = __expf(s);
        rowpart += e;
        E[(size_t)bz * SS + (size_t)gm * 2048 + gn] = (__bf16)e;
      }
      rowpart += __shfl_xor(rowpart, 1);
      rowpart += __shfl_xor(rowpart, 2);
      rowpart += __shfl_xor(rowpart, 4);
      rowpart += __shfl_xor(rowpart, 8);
      if (lo == 0) atomicAdd(&L[(size_t)bz * 2048 + gm], rowpart);
    }
  }
}

// CTX/OUT fused: out = (E @ VWoT^T) / L + bo -> fp32. grid (64,1,4),
// same 2x4 XCD patch decode (A 2MB + B 2MB = 4MB ~ L2).
__global__ __launch_bounds__(512, 2) void ctx_k(
    const __bf16* __restrict__ E, const __bf16* __restrict__ VWoT,
    const float* __restrict__ L, const float* __restrict__ bo,
    float* __restrict__ out) {
  __shared__ __bf16 As[2 * 256 * 64];
  __shared__ __bf16 Bs[2 * 128 * 64];
  const int tid = threadIdx.x;
  ACC_INIT(2);
  const int bz = blockIdx.z;
  const int sid = blockIdx.x;
  const int xcd = sid & 7, k = sid >> 3;
  const int m0 = ((xcd >> 1) * 2 + (k >> 2)) * 256; // s-tile 0..7
  const int n0 = ((xcd & 1) * 4 + (k & 3)) * 128;   // e-tile 0..7
  gemm_core8<128>(E + (size_t)bz * SS, VWoT + (size_t)bz * SH, As, Bs, acc,
                  m0, n0, 2048, 2048, 2048, tid);
  EPI_IDS();
#pragma unroll
  for (int mt = 0; mt < 8; mt++) {
    const int gmb = m0 + wm * 128 + mt * 16 + quad * 4;
#pragma unroll
    for (int nt = 0; nt < 2; nt++) {
      const int gn = n0 + wn * 32 + nt * 16 + lo;
      const float bo_ = bo[gn];
#pragma unroll
      for (int r = 0; r < 4; r++) {
        const int gm = gmb + r;
        const float inv = 1.0f / L[(size_t)bz * 2048 + gm];
        out[((size_t)bz * 2048 + gm) * 1024 + gn] = acc[mt][nt][r] * inv + bo_;
      }
    }
  }
}

// WvWo: MTb[e][d] = (Wv @ Wo)[d][e]  (B-operand for qkv chunk 2).
// C2[d][e] = sum_c Wvb[d][c] * Wt3[e][c]; stored transposed. grid (8,4).
__global__ __launch_bounds__(512, 2) void wvwo_k(
    const __bf16* __restrict__ Wvb, const __bf16* __restrict__ Wt3,
    __bf16* __restrict__ MTb) {
  __shared__ __bf16 As[2 * 256 * 64];
  __shared__ __bf16 Bs[2 * 128 * 64];
  const int tid = threadIdx.x;
  ACC_INIT(2);
  const int m0 = blockIdx.y * 256;   // d
  const int n0 = blockIdx.x * 128;   // e
  gemm_core8<128>(Wvb, Wt3, As, Bs, acc, m0, n0, 1024, 1024, 1024, tid);
  EPI_IDS();
#pragma unroll
  for (int mt = 0; mt < 8; mt++) {
    const int d0 = m0 + wm * 128 + mt * 16 + quad * 4;
#pragma unroll
    for (int nt = 0; nt < 2; nt++) {
      const int e = n0 + wn * 32 + nt * 16 + lo;
      bf16x4 pk;
#pragma unroll
      for (int r = 0; r < 4; r++) pk[r] = (__bf16)acc[mt][nt][r];
      *(bf16x4*)(MTb + (size_t)e * 1024 + d0) = pk;
    }
  }
}

// bvWo[e] = sum_d bv[d] * Wo[d][e] = sum_d bv[d] * Wt3[e][d]. grid (4).
__global__ __launch_bounds__(256) void bvwo_k(
    const float* __restrict__ bv, const __bf16* __restrict__ Wt3,
    float* __restrict__ bvWo) {
  const int e = blockIdx.x * 256 + threadIdx.x;
  const __bf16* row = Wt3 + (size_t)e * 1024;
  float s = 0.f;
  for (int d = 0; d < 1024; d += 8) {
    bf16x8 wv = *(const bf16x8*)(row + d);
#pragma unroll
    for (int j = 0; j < 8; j++) s += bv[d + j] * (float)wv[j];
  }
  bvWo[e] = s;
}

// Prep, grid (16,16,9):
//   z=0,1,3 : transpose+convert W (1024x1024 fp32 K x N) -> bf16 N x K plane.
//   z=2     : PLAIN convert Wv -> bf16 (row-major, for wvwo_k's A operand).
//   z=4     : convert fp32 X -> bf16; zero L (first 32 blocks).
//   z=5..8  : pack int32 mask (4*2048*2048) -> bitmask Pk, quarter per plane.
__global__ __launch_bounds__(256) void prep_k(
    const float* __restrict__ X, __bf16* __restrict__ Xb,
    const float* __restrict__ Wq, const float* __restrict__ Wk,
    const float* __restrict__ Wv, const float* __restrict__ Wo,
    __bf16* __restrict__ Wt, float* __restrict__ L,
    const int* __restrict__ mask, unsigned* __restrict__ Pk) {
  const int z = blockIdx.z;
  const int tid = threadIdx.x;
  const int bid = blockIdx.y * 16 + blockIdx.x;  // 0..255
  if (z == 4) {
    if (bid < 32) L[bid * 256 + tid] = 0.f;
#pragma unroll
    for (int k = 0; k < 32; k++) {
      const size_t i = (size_t)(bid * 256 + tid) + (size_t)k * 65536;
      const float4 v = ((const float4*)X)[i];
      bf16x4 o;
      o[0] = (__bf16)v.x; o[1] = (__bf16)v.y; o[2] = (__bf16)v.z; o[3] = (__bf16)v.w;
      ((bf16x4*)Xb)[i] = o;
    }
    return;
  }
  if (z >= 5) {
    const int base = (z - 5) * 131072;  // u32 words per quarter
#pragma unroll
    for (int k = 0; k < 2; k++) {
      const int idx = base + bid * 512 + k * 256 + tid;
      const int4* m4 = (const int4*)(mask + (size_t)idx * 32);
      unsigned bits = 0;
#pragma unroll
      for (int q = 0; q < 8; q++) {
        int4 v = m4[q];
        bits |= (v.x != 0 ? 1u : 0u) << (q * 4);
        bits |= (v.y != 0 ? 1u : 0u) << (q * 4 + 1);
        bits |= (v.z != 0 ? 1u : 0u) << (q * 4 + 2);
        bits |= (v.w != 0 ? 1u : 0u) << (q * 4 + 3);
      }
      Pk[idx] = bits;
    }
    return;
  }
  if (z == 2) {
    __bf16* D = Wt + (size_t)2 * 1024 * 1024;
#pragma unroll
    for (int k = 0; k < 4; k++) {
      const size_t i = (size_t)(bid * 256 + tid) + (size_t)k * 65536;
      const float4 v = ((const float4*)Wv)[i];
      bf16x4 o;
      o[0] = (__bf16)v.x; o[1] = (__bf16)v.y; o[2] = (__bf16)v.z; o[3] = (__bf16)v.w;
      ((bf16x4*)D)[i] = o;
    }
    return;
  }
  const float* W = (z == 0) ? Wq : (z == 1) ? Wk : Wo;
  __bf16* D = Wt + (size_t)z * 1024 * 1024;
  __shared__ float T[64][65];
  const int r0 = blockIdx.y * 64, c0 = blockIdx.x * 64;
#pragma unroll
  for (int i = 0; i < 16; i++) {
    const int e = i * 256 + tid;
    const int r = e >> 6, c = e & 63;
    T[r][c] = W[(size_t)(r0 + r) * 1024 + c0 + c];
  }
  __syncthreads();
#pragma unroll
  for (int i = 0; i < 16; i++) {
    const int e = i * 256 + tid;
    const int rr = e >> 6, cc = e & 63;
    D[(size_t)(c0 + rr) * 1024 + r0 + cc] = (__bf16)T[cc][rr];
  }
}

extern "C" void kernel_launch(void* const* d_in, const int* in_sizes, int n_in,
                              void* d_out, int out_size, void* d_ws, size_t ws_size,
                              hipStream_t stream) {
  (void)in_sizes; (void)n_in; (void)out_size; (void)ws_size;
  const int H = 1024;

  const float* X   = (const float*)d_in[0];
  const int*   msk = (const int*)d_in[1];
  const float* Wq  = (const float*)d_in[2];
  const float* bq  = (const float*)d_in[3];
  const float* Wk  = (const float*)d_in[4];
  const float* bk  = (const float*)d_in[5];
  const float* Wv  = (const float*)d_in[6];
  const float* bv  = (const float*)d_in[7];
  const float* Wo  = (const float*)d_in[8];
  const float* bo  = (const float*)d_in[9];
  float* out = (float*)d_out;

  // Workspace (~113.3 MB):
  //   Xb[16.8M] Wt[8.4M: Wq^T|Wk^T|Wv(plain)|Wo^T] MTb[2.1M] QK[33.6M]
  //   VWoT[16.8M] E[33.6M] L[32K] bvWo[4K] Pk[2.1M]
  char* ws = (char*)d_ws;
  __bf16* Xb   = (__bf16*)ws;
  __bf16* Wt   = Xb + (size_t)8192 * H;
  __bf16* MTb  = Wt + (size_t)4 * H * H;
  __bf16* QK   = MTb + (size_t)H * H;
  __bf16* VWoT = QK + (size_t)2 * 8192 * H;
  __bf16* E    = VWoT + (size_t)4 * H * 2048;
  float*  L    = (float*)(E + (size_t)4 * SS);
  float*  bvWo = L + 8192;
  unsigned* Pk = (unsigned*)(bvWo + 1024);

  dim3 blk256(256), blk512(512);

  prep_k<<<dim3(16, 16, 9), blk256, 0, stream>>>(X, Xb, Wq, Wk, Wv, Wo, Wt, L, msk, Pk);
  bvwo_k<<<dim3(4), blk256, 0, stream>>>(bv, Wt + (size_t)3 * H * H, bvWo);
  wvwo_k<<<dim3(8, 4), blk512, 0, stream>>>(Wt + (size_t)2 * H * H, Wt + (size_t)3 * H * H, MTb);
  qkv_k<<<dim3(24, 32), blk512, 0, stream>>>(Xb, Wt, MTb, bq, bk, bvWo, QK, VWoT);
  mid_k<<<dim3(64, 1, 4), blk512, 0, stream>>>(QK, E, Pk, L);
  ctx_k<<<dim3(64, 1, 4), blk512, 0, stream>>>(E, VWoT, L, bo, out);
}